// Round 14
// baseline (3722.107 us; speedup 1.0000x reference)
//
#include <hip/hip_runtime.h>
#include <math.h>

typedef unsigned int u32;
typedef unsigned short u16;

#define EPS 1e-5f
#define PTS 64   // points per tile (= one wavefront)

// stats/scale-shift offsets into g_acc / g_st (floats)
#define S0 0
#define Q0 16
#define S1 32
#define Q1 96
#define S2 160
#define Q2 288
#define S3 416
#define Q3 672

#define Z4S 132  // z4 LDS stride in floats (16B-aligned rows, bank-spread)

__device__ float g_acc[1024];  // sums (S*), sum-of-squares (Q*), cross-terms (Q0+3..5)
__device__ float g_st[1024];   // per-feature scale (at S*) and shift (at Q*)
__device__ int   g_is64;       // 1 if unq buffer is int64
__device__ int   g_inv64;      // 1 if unq_inv buffer is int64
__device__ int   g_umax;       // max(unq_inv)
__device__ long  g_U;          // segment count = g_umax + 1

__device__ __forceinline__ float bf2f(u16 b){ return __uint_as_float(((u32)b) << 16); }
__device__ __forceinline__ u16 f2bf(float f){
  u32 u = __float_as_uint(f);
  return (u16)((u + 0x7fffu + ((u >> 16) & 1u)) >> 16);  // RNE
}

// float atomic max via sign-split HW atomics; requires init to -inf.
__device__ __forceinline__ void atomicMaxF32(float* addr, float v){
  if (v == 0.f) v = 0.f;            // canonicalize -0.0 -> +0.0
  if (v >= 0.f) atomicMax((int*)addr, __float_as_int(v));
  else          atomicMin((u32*)addr, __float_as_uint(v));
}

__device__ __forceinline__ void waveRedArr(float* v, int n){
  #pragma unroll
  for (int off = 32; off > 0; off >>= 1)
    for (int i = 0; i < n; ++i) v[i] += __shfl_xor(v[i], off, 64);
}

// 16 outputs (bias-init); h from LDS bf16 tile hsrc[FIN][PTS]; weights via
// wave-uniform (readfirstlane) scalar addressing -> s_load.
template<int FIN, int FOUT>
__device__ __forceinline__ void chunk16(const u16* hsrc, int lane,
    const float* __restrict__ W, const float* __restrict__ bias,
    int j0, float acc[16])
{
  const int j0u = __builtin_amdgcn_readfirstlane(j0);
  #pragma unroll
  for (int jj = 0; jj < 16; ++jj) acc[jj] = bias[j0u + jj];
  #pragma unroll 4
  for (int k = 0; k < FIN; ++k){
    const float hk = bf2f(hsrc[k*PTS + lane]);
    const float* Wr = W + (long)k*FOUT + j0u;
    #pragma unroll
    for (int jj = 0; jj < 16; ++jj) acc[jj] = fmaf(hk, Wr[jj], acc[jj]);
  }
}

// 16-output accumulate-only variant: rows k0..k0+FIN-1 of W, h from hsrc.
template<int FIN, int FOUT>
__device__ __forceinline__ void chunk16_acc(const u16* hsrc, int lane,
    const float* __restrict__ W, int j0, int k0, float acc[16])
{
  const int j0u = __builtin_amdgcn_readfirstlane(j0);
  #pragma unroll 4
  for (int k = 0; k < FIN; ++k){
    const float hk = bf2f(hsrc[k*PTS + lane]);
    const float* Wr = W + (long)(k0 + k)*FOUT + j0u;
    #pragma unroll
    for (int jj = 0; jj < 16; ++jj) acc[jj] = fmaf(hk, Wr[jj], acc[jj]);
  }
}

__device__ __forceinline__ void emitStats(float acc[16], bool valid, int lane, int j0,
                                          float* bs, float* bq){
  #pragma unroll
  for (int jj = 0; jj < 16; ++jj){
    float v = valid ? acc[jj] : 0.f;
    float sq[2] = {v, v*v};
    waveRedArr(sq, 2);
    if (lane == 0){ atomicAdd(&bs[j0+jj], sq[0]); atomicAdd(&bq[j0+jj], sq[1]); }
  }
}
__device__ __forceinline__ void emitH(float acc[16], int lane, int j0u, int soff, int qoff, u16* hdst){
  #pragma unroll
  for (int jj = 0; jj < 16; ++jj){
    float z = fmaxf(acc[jj]*g_st[soff+j0u+jj] + g_st[qoff+j0u+jj], 0.f);
    hdst[(j0u+jj)*PTS + lane] = f2bf(z);
  }
}

__global__ void kreset(){
  if (threadIdx.x == 0) g_umax = 0;
  for (int i = threadIdx.x; i < 1024; i += blockDim.x) g_acc[i] = 0.f;
}

// int64 data (values < 2^31): all odd 32-bit words are zero. int32: not.
__global__ void ksniff_inv(const u32* __restrict__ w, long nwords){
  __shared__ int any;
  if (threadIdx.x == 0) any = 0;
  __syncthreads();
  for (long i = 2L*threadIdx.x + 1; i < nwords; i += 2L*blockDim.x){
    if (w[i] != 0u){ any = 1; break; }
  }
  __syncthreads();
  if (threadIdx.x == 0) g_inv64 = (any == 0) ? 1 : 0;
}

__global__ __launch_bounds__(256) void ksegU(const void* __restrict__ invv, int N){
  const int inv64 = g_inv64;
  int m = 0;
  const int stride = gridDim.x*blockDim.x;
  if (inv64){
    const long long* q = (const long long*)invv;
    for (int i = blockIdx.x*blockDim.x + threadIdx.x; i < N; i += stride)
      m = max(m, (int)q[i]);
  } else {
    const int* q = (const int*)invv;
    for (int i = blockIdx.x*blockDim.x + threadIdx.x; i < N; i += stride)
      m = max(m, q[i]);
  }
  #pragma unroll
  for (int off = 32; off > 0; off >>= 1) m = max(m, __shfl_xor(m, off, 64));
  if ((threadIdx.x & 63) == 0) atomicMax(&g_umax, m);
}

__global__ void ksetU(){
  if (threadIdx.x == 0) g_U = (long)g_umax + 1;
}

__global__ void ksniff_unq(const u32* __restrict__ w){
  const long nwords = 3L*g_U;
  __shared__ int any;
  if (threadIdx.x == 0) any = 0;
  __syncthreads();
  for (long i = 2L*threadIdx.x + 1; i < nwords; i += 2L*blockDim.x){
    if (w[i] != 0u){ any = 1; break; }
  }
  __syncthreads();
  if (threadIdx.x == 0) g_is64 = (any == 0) ? 1 : 0;
}

// init pooled region [3U, 131U) to -inf (f32)
__global__ void kpoolinit(float* __restrict__ out, long outSize){
  const long U = g_U;
  const long lo = 3*U;
  const long hi = (131*U < outSize) ? 131*U : outSize;
  const long i0 = (long)blockIdx.x*blockDim.x + threadIdx.x;
  const long stride = (long)gridDim.x*blockDim.x;
  for (long i = lo + i0; i < hi; i += stride) out[i] = -INFINITY;
}

// unq coords into [0, 3U) as f32
__global__ void kunq(float* __restrict__ out, const void* __restrict__ unqv, long outSize){
  const long U = g_U;
  const long n = (3*U < outSize) ? 3*U : outSize;
  const long i0 = (long)blockIdx.x*blockDim.x + threadIdx.x;
  const long stride = (long)gridDim.x*blockDim.x;
  if (g_is64){
    const long long* uq = (const long long*)unqv;
    for (long i = i0; i < n; i += stride) out[i] = (float)uq[i];
  } else {
    const int* uq = (const int*)unqv;
    for (long i = i0; i < n; i += stride) out[i] = (float)uq[i];
  }
}

// stats0: 9 sums over x: Σx (3), Σx² (3), Σxy,Σxz,Σyz (3)
__global__ __launch_bounds__(256) void kstats0(const float* __restrict__ x, int N){
  __shared__ float red[4][9];
  float a[9];
  #pragma unroll
  for (int i = 0; i < 9; ++i) a[i] = 0.f;
  const int stride = gridDim.x*blockDim.x;
  for (int p = blockIdx.x*blockDim.x + threadIdx.x; p < N; p += stride){
    float v0 = x[(size_t)p*3 + 0], v1 = x[(size_t)p*3 + 1], v2 = x[(size_t)p*3 + 2];
    a[0]+=v0; a[1]+=v1; a[2]+=v2;
    a[3]+=v0*v0; a[4]+=v1*v1; a[5]+=v2*v2;
    a[6]+=v0*v1; a[7]+=v0*v2; a[8]+=v1*v2;
  }
  waveRedArr(a, 9);
  const int w = threadIdx.x >> 6, lane = threadIdx.x & 63;
  if (lane == 0){
    #pragma unroll
    for (int i = 0; i < 9; ++i) red[w][i] = a[i];
  }
  __syncthreads();
  if (threadIdx.x < 9){
    float t = 0.f;
    #pragma unroll
    for (int k = 0; k < 4; ++k) t += red[k][threadIdx.x];
    const int c = threadIdx.x;
    atomicAdd(&g_acc[(c < 3) ? (S0 + c) : (Q0 + (c - 3))], t);
  }
}

// generic BN finalize from accumulated stats (BN0, BN2, BN3)
__global__ void kfin(int dim, int soff, int qoff,
                     const float* __restrict__ g, const float* __restrict__ b, float invN){
  const int j = threadIdx.x;
  if (j >= dim) return;
  const float m = g_acc[soff+j]*invN;
  const float var = fmaxf(g_acc[qoff+j]*invN - m*m, 0.f);
  const float s = g[j]*rsqrtf(var + EPS);
  g_st[soff+j] = s;
  g_st[qoff+j] = b[j] - m*s;
}

// analytic BN1 finalize (pass-1 elimination); see R9 notes.
__global__ void kfin1(const float* __restrict__ g1, const float* __restrict__ b1bn,
                      const float* __restrict__ W1, const float* __restrict__ b1lin,
                      float invN){
  const int j = threadIdx.x;
  if (j >= 64) return;
  float m0[3], s0[3], t0[3];
  #pragma unroll
  for (int c = 0; c < 3; ++c){
    m0[c] = g_acc[S0+c]*invN;
    s0[c] = g_st[S0+c];
    t0[c] = g_st[Q0+c];
  }
  float C[3][3];
  C[0][0] = g_acc[Q0+0]*invN - m0[0]*m0[0];
  C[1][1] = g_acc[Q0+1]*invN - m0[1]*m0[1];
  C[2][2] = g_acc[Q0+2]*invN - m0[2]*m0[2];
  C[0][1] = C[1][0] = g_acc[Q0+3]*invN - m0[0]*m0[1];
  C[0][2] = C[2][0] = g_acc[Q0+4]*invN - m0[0]*m0[2];
  C[1][2] = C[2][1] = g_acc[Q0+5]*invN - m0[1]*m0[2];

  float wj[3] = {W1[0*64 + j], W1[1*64 + j], W1[2*64 + j]};
  float mean = b1lin[j];
  #pragma unroll
  for (int c = 0; c < 3; ++c) mean += (m0[c]*s0[c] + t0[c])*wj[c];
  float var = 0.f;
  #pragma unroll
  for (int a = 0; a < 3; ++a)
    #pragma unroll
    for (int b = 0; b < 3; ++b)
      var += wj[a]*s0[a]*wj[b]*s0[b]*C[a][b];
  var = fmaxf(var, 0.f);
  const float sc = g1[j]*rsqrtf(var + EPS);
  g_st[S1+j] = sc;
  g_st[Q1+j] = b1bn[j] - mean*sc;
}

// STAGE 2..3: stats for z2..z3; STAGE 4: final layer + coalesced segment-max.
// WSMODE: 0 = none; 1 (STAGE 3) = store pre-BN z3 as bf16 to ws[m*N+p];
//         2 (STAGE 4) = load bf16 z3 from ws, skip L1-L3 recompute.
// LDS overlay (u16 units), z4 = f32[64][Z4S] = 16896 u16:
//   STAGE 2:           h1 @0 (4096)                          -> buf 4096
//   STAGE 3:           h2 @0 (8192), h1 @8192 (4096)         -> buf 12288
//   STAGE 4 WSMODE 0:  h2 @0, h1 @8192, h3half @8192 (8192, overlays dead h1),
//                      z4 overlays all                        -> buf 16896 (33.8 KB)
//   STAGE 4 WSMODE 2:  h3 @0 (16384), z4 overlays             -> buf 16896 (33.8 KB)
template<int STAGE, int WSMODE>
__global__ __launch_bounds__(256) void kpass(
    const float* __restrict__ x, const void* __restrict__ unq_inv_v,
    const float* __restrict__ W1, const float* __restrict__ b1,
    const float* __restrict__ W2, const float* __restrict__ b2,
    const float* __restrict__ W3, const float* __restrict__ b3,
    const float* __restrict__ W4, const float* __restrict__ b4,
    u16* __restrict__ z3ws, float* __restrict__ out, int N, long outSize)
{
  constexpr bool RECOMP = (WSMODE != 2);
  constexpr bool ST4    = (STAGE >= 4);
  constexpr int BUF_U16 = (STAGE == 2) ? 4096 : (STAGE == 3) ? 12288 : 16896;
  __shared__ u16 buf[BUF_U16];
  __shared__ float bs[(STAGE <= 3) ? 256 : 1], bq[(STAGE <= 3) ? 256 : 1];
  __shared__ int seg_s[ST4 ? 64 : 1];

  u16* const h1s = buf + ((STAGE >= 3 && RECOMP) ? 8192 : 0);
  u16* const h2s = buf;                 // stages >= 3, recompute
  u16* const h3h = buf + 8192;          // stage 4 recompute: 128-feature half tile
  u16* const h3s = buf;                 // stage 4 mode-2: full 256-feature tile
  float* const z4 = (float*)buf;        // stage 4 flush staging [64][Z4S]

  const long U = g_U;
  const int inv64 = g_inv64;
  const long loEl = 3*U;
  const long hiEl = (131*U < outSize) ? 131*U : outSize;

  const int tid  = threadIdx.x;
  const int w    = tid >> 6;
  const int lane = tid & 63;

  if constexpr (STAGE <= 3){
    for (int i = tid; i < 256; i += 256){ bs[i] = 0.f; bq[i] = 0.f; }
    __syncthreads();
  }

  const int nb = (N + PTS - 1) / PTS;
  for (int b = blockIdx.x; b < nb; b += gridDim.x){
    const int p = b*PTS + lane;
    const bool valid = p < N;

    if constexpr (RECOMP){
      { // bn0 + layer 1: 3 -> 64 (feeds h1)
        float h0[3];
        #pragma unroll
        for (int c = 0; c < 3; ++c){
          float xv = valid ? x[(size_t)p*3 + c] : 0.f;
          h0[c] = xv*g_st[S0 + c] + g_st[Q0 + c];
        }
        const int j0u = __builtin_amdgcn_readfirstlane(w*16);
        float acc[16];
        #pragma unroll
        for (int jj = 0; jj < 16; ++jj) acc[jj] = b1[j0u + jj];
        #pragma unroll
        for (int k = 0; k < 3; ++k){
          const float* Wr = W1 + k*64 + j0u;
          #pragma unroll
          for (int jj = 0; jj < 16; ++jj) acc[jj] = fmaf(h0[k], Wr[jj], acc[jj]);
        }
        emitH(acc, lane, j0u, S1, Q1, h1s);
      }
      { // layer 2: 64 -> 128
        __syncthreads();
        #pragma unroll
        for (int c = 0; c < 2; ++c){
          const int j0 = w*32 + c*16;
          float acc[16];
          chunk16<64,128>(h1s, lane, W2, b2, j0, acc);
          if constexpr (STAGE == 2) emitStats(acc, valid, lane, j0, bs, bq);
          else emitH(acc, lane, __builtin_amdgcn_readfirstlane(j0), S2, Q2, h2s);
        }
      }
    }
    if constexpr (STAGE == 3){ // layer 3 stats (+ optional bf16 z3 store)
      __syncthreads();
      #pragma unroll
      for (int c = 0; c < 4; ++c){
        const int j0 = w*64 + c*16;
        float acc[16];
        chunk16<128,256>(h2s, lane, W3, b3, j0, acc);
        emitStats(acc, valid, lane, j0, bs, bq);
        if constexpr (WSMODE == 1){
          if (valid){
            #pragma unroll
            for (int jj = 0; jj < 16; ++jj)
              z3ws[(size_t)(j0 + jj)*N + p] = f2bf(acc[jj]);  // coalesced bf16 store
          }
        }
      }
    }
    if constexpr (ST4){
      float accA[16], accB[16];
      if constexpr (RECOMP){
        // L3+L4 in two 128-feature halves over h3h (overlays dead h1)
        const int jA = __builtin_amdgcn_readfirstlane(w*32);
        #pragma unroll
        for (int jj = 0; jj < 16; ++jj){ accA[jj] = b4[jA + jj]; accB[jj] = b4[jA + 16 + jj]; }
        #pragma unroll
        for (int half = 0; half < 2; ++half){
          __syncthreads();  // h2 ready / previous-half L4 reads done
          #pragma unroll
          for (int c = 0; c < 2; ++c){
            const int j0 = half*128 + w*32 + c*16;
            float acc[16];
            chunk16<128,256>(h2s, lane, W3, b3, j0, acc);
            const int j0u = __builtin_amdgcn_readfirstlane(j0);
            const int r0  = j0u - half*128;
            #pragma unroll
            for (int jj = 0; jj < 16; ++jj){
              float z = fmaxf(acc[jj]*g_st[S3+j0u+jj] + g_st[Q3+j0u+jj], 0.f);
              h3h[(r0+jj)*PTS + lane] = f2bf(z);
            }
          }
          __syncthreads();  // h3 half ready
          chunk16_acc<128,128>(h3h, lane, W4, w*32,      half*128, accA);
          chunk16_acc<128,128>(h3h, lane, W4, w*32 + 16, half*128, accB);
        }
      } else {
        // mode 2: load bf16 z3 from ws, bn3+relu -> full h3
        const int j0u = __builtin_amdgcn_readfirstlane(w*64);
        #pragma unroll 8
        for (int mm = 0; mm < 64; ++mm){
          const int m = j0u + mm;
          float z = valid ? bf2f(z3ws[(size_t)m*N + p]) : 0.f;
          z = fmaxf(z*g_st[S3 + m] + g_st[Q3 + m], 0.f);
          h3s[m*PTS + lane] = f2bf(z);
        }
        __syncthreads();  // h3 ready
        chunk16<256,128>(h3s, lane, W4, b4, w*32,      accA);
        chunk16<256,128>(h3s, lane, W4, b4, w*32 + 16, accB);
      }
      // common tail: seg, z4 transpose staging, coalesced flush
      if (w == 0){
        long seg = -1;
        if (valid){
          if (inv64) seg = (long)((const long long*)unq_inv_v)[p];
          else       seg = (long)((const int*)unq_inv_v)[p];
        }
        seg_s[lane] = (seg >= 0 && seg < U &&
                       loEl + seg*128 + 128 <= hiEl) ? (int)seg : -1;
      }
      __syncthreads();  // all LDS reads done -> z4 space free; seg_s ready
      {
        float4* dst = (float4*)&z4[lane*Z4S + w*32];
        dst[0] = make_float4(accA[ 0],accA[ 1],accA[ 2],accA[ 3]);
        dst[1] = make_float4(accA[ 4],accA[ 5],accA[ 6],accA[ 7]);
        dst[2] = make_float4(accA[ 8],accA[ 9],accA[10],accA[11]);
        dst[3] = make_float4(accA[12],accA[13],accA[14],accA[15]);
        dst[4] = make_float4(accB[ 0],accB[ 1],accB[ 2],accB[ 3]);
        dst[5] = make_float4(accB[ 4],accB[ 5],accB[ 6],accB[ 7]);
        dst[6] = make_float4(accB[ 8],accB[ 9],accB[10],accB[11]);
        dst[7] = make_float4(accB[12],accB[13],accB[14],accB[15]);
      }
      __syncthreads();  // z4 complete
      #pragma unroll 4
      for (int pt2 = 0; pt2 < 64; pt2 += 2){
        const int pt = pt2 + (tid >> 7);
        const int f  = tid & 127;
        const int sg = seg_s[pt];
        if (sg >= 0)
          atomicMaxF32(out + loEl + (long)sg*128 + f, z4[pt*Z4S + f]);
      }
    }
    __syncthreads();  // protect LDS across tile iterations
  }

  if constexpr (STAGE <= 3){
    const int dim  = (STAGE == 2) ? 128 : 256;
    const int soff = (STAGE == 2) ? S2 : S3;
    const int qoff = (STAGE == 2) ? Q2 : Q3;
    for (int j = tid; j < dim; j += 256){
      atomicAdd(&g_acc[soff + j], bs[j]);
      atomicAdd(&g_acc[qoff + j], bq[j]);
    }
  }
}

extern "C" void kernel_launch(void* const* d_in, const int* in_sizes, int n_in,
                              void* d_out, int out_size, void* d_ws, size_t ws_size,
                              hipStream_t stream)
{
  const float* x       = (const float*)d_in[0];
  const void*  unq     = d_in[2];
  const void*  unq_inv = d_in[3];
  const float* bn_g[4] = {(const float*)d_in[4], (const float*)d_in[6], (const float*)d_in[8], (const float*)d_in[10]};
  const float* bn_b[4] = {(const float*)d_in[5], (const float*)d_in[7], (const float*)d_in[9], (const float*)d_in[11]};
  const float* W1 = (const float*)d_in[12]; const float* b1 = (const float*)d_in[13];
  const float* W2 = (const float*)d_in[14]; const float* b2 = (const float*)d_in[15];
  const float* W3 = (const float*)d_in[16]; const float* b3 = (const float*)d_in[17];
  const float* W4 = (const float*)d_in[18]; const float* b4 = (const float*)d_in[19];

  const int N = in_sizes[0] / 3;
  float* out = (float*)d_out;
  u16* z3ws = (u16*)d_ws;
  const float invN = 1.0f / (float)N;
  const long outSize = (long)out_size;
  const bool useWs = (ws_size >= (size_t)N * 256 * sizeof(u16));  // 512 MB bf16 z3

  kreset<<<1, 1024, 0, stream>>>();
  ksniff_inv<<<1, 1024, 0, stream>>>((const u32*)unq_inv, (long)N);
  ksegU<<<512, 256, 0, stream>>>(unq_inv, N);
  ksetU<<<1, 64, 0, stream>>>();
  ksniff_unq<<<1, 1024, 0, stream>>>((const u32*)unq);
  kpoolinit<<<2048, 256, 0, stream>>>(out, outSize);

  kstats0<<<1024, 256, 0, stream>>>(x, N);
  kfin<<<1, 256, 0, stream>>>(3, S0, Q0, bn_g[0], bn_b[0], invN);
  kfin1<<<1, 64, 0, stream>>>(bn_g[1], bn_b[1], W1, b1, invN);

  kpass<2,0><<<1792, 256, 0, stream>>>(x, unq_inv, W1,b1,W2,b2,W3,b3,W4,b4, z3ws, out, N, outSize);
  kfin<<<1, 256, 0, stream>>>(128, S2, Q2, bn_g[2], bn_b[2], invN);

  if (useWs){
    kpass<3,1><<<1536, 256, 0, stream>>>(x, unq_inv, W1,b1,W2,b2,W3,b3,W4,b4, z3ws, out, N, outSize);
    kfin<<<1, 256, 0, stream>>>(256, S3, Q3, bn_g[3], bn_b[3], invN);
    kpass<4,2><<<1024, 256, 0, stream>>>(x, unq_inv, W1,b1,W2,b2,W3,b3,W4,b4, z3ws, out, N, outSize);
  } else {
    kpass<3,0><<<1536, 256, 0, stream>>>(x, unq_inv, W1,b1,W2,b2,W3,b3,W4,b4, z3ws, out, N, outSize);
    kfin<<<1, 256, 0, stream>>>(256, S3, Q3, bn_g[3], bn_b[3], invN);
    kpass<4,0><<<1024, 256, 0, stream>>>(x, unq_inv, W1,b1,W2,b2,W3,b3,W4,b4, z3ws, out, N, outSize);
  }

  kunq<<<2048, 256, 0, stream>>>(out, unq, outSize);
}

// Round 15
// 2526.182 us; speedup vs baseline: 1.4734x; 1.4734x over previous
//
#include <hip/hip_runtime.h>
#include <math.h>

typedef unsigned int u32;
typedef unsigned short u16;

#define EPS 1e-5f
#define PTS 64   // points per tile (= one wavefront)

// stats/scale-shift offsets into g_acc / g_st (floats)
#define S0 0
#define Q0 16
#define S1 32
#define Q1 96
#define S2 160
#define Q2 288
#define S3 416
#define Q3 672

#define Z4S 132  // z4 LDS stride in floats

__device__ float g_acc[1024];
__device__ float g_st[1024];
__device__ int   g_is64;
__device__ int   g_inv64;
__device__ int   g_umax;
__device__ long  g_U;

__device__ __forceinline__ float bf2f(u16 b){ return __uint_as_float(((u32)b) << 16); }
__device__ __forceinline__ u16 f2bf(float f){
  u32 u = __float_as_uint(f);
  return (u16)((u + 0x7fffu + ((u >> 16) & 1u)) >> 16);  // RNE
}

__device__ __forceinline__ void atomicMaxF32(float* addr, float v){
  if (v == 0.f) v = 0.f;
  if (v >= 0.f) atomicMax((int*)addr, __float_as_int(v));
  else          atomicMin((u32*)addr, __float_as_uint(v));
}

__device__ __forceinline__ void waveRedArr(float* v, int n){
  #pragma unroll
  for (int off = 32; off > 0; off >>= 1)
    for (int i = 0; i < n; ++i) v[i] += __shfl_xor(v[i], off, 64);
}

// 16 outputs (bias-init); h from LDS bf16 tile hsrc[FIN][PTS]; weights via
// wave-uniform scalar addressing -> s_load.
template<int FIN, int FOUT>
__device__ __forceinline__ void chunk16(const u16* hsrc, int lane,
    const float* __restrict__ W, const float* __restrict__ bias,
    int j0, float acc[16])
{
  const int j0u = __builtin_amdgcn_readfirstlane(j0);
  #pragma unroll
  for (int jj = 0; jj < 16; ++jj) acc[jj] = bias[j0u + jj];
  #pragma unroll 4
  for (int k = 0; k < FIN; ++k){
    const float hk = bf2f(hsrc[k*PTS + lane]);
    const float* Wr = W + (long)k*FOUT + j0u;
    #pragma unroll
    for (int jj = 0; jj < 16; ++jj) acc[jj] = fmaf(hk, Wr[jj], acc[jj]);
  }
}

// accumulate-only variant: rows k0..k0+FIN-1 of W
template<int FIN, int FOUT>
__device__ __forceinline__ void chunk16_acc(const u16* hsrc, int lane,
    const float* __restrict__ W, int j0, int k0, float acc[16])
{
  const int j0u = __builtin_amdgcn_readfirstlane(j0);
  #pragma unroll 4
  for (int k = 0; k < FIN; ++k){
    const float hk = bf2f(hsrc[k*PTS + lane]);
    const float* Wr = W + (long)(k0 + k)*FOUT + j0u;
    #pragma unroll
    for (int jj = 0; jj < 16; ++jj) acc[jj] = fmaf(hk, Wr[jj], acc[jj]);
  }
}

__device__ __forceinline__ void emitStats(float acc[16], bool valid, int lane, int j0,
                                          float* bs, float* bq){
  #pragma unroll
  for (int jj = 0; jj < 16; ++jj){
    float v = valid ? acc[jj] : 0.f;
    float sq[2] = {v, v*v};
    waveRedArr(sq, 2);
    if (lane == 0){ atomicAdd(&bs[j0+jj], sq[0]); atomicAdd(&bq[j0+jj], sq[1]); }
  }
}
__device__ __forceinline__ void emitH(float acc[16], int lane, int j0u, int soff, int qoff, u16* hdst){
  #pragma unroll
  for (int jj = 0; jj < 16; ++jj){
    float z = fmaxf(acc[jj]*g_st[soff+j0u+jj] + g_st[qoff+j0u+jj], 0.f);
    hdst[(j0u+jj)*PTS + lane] = f2bf(z);
  }
}

__global__ void kreset(){
  if (threadIdx.x == 0) g_umax = 0;
  for (int i = threadIdx.x; i < 1024; i += blockDim.x) g_acc[i] = 0.f;
}

__global__ void ksniff_inv(const u32* __restrict__ w, long nwords){
  __shared__ int any;
  if (threadIdx.x == 0) any = 0;
  __syncthreads();
  for (long i = 2L*threadIdx.x + 1; i < nwords; i += 2L*blockDim.x){
    if (w[i] != 0u){ any = 1; break; }
  }
  __syncthreads();
  if (threadIdx.x == 0) g_inv64 = (any == 0) ? 1 : 0;
}

__global__ __launch_bounds__(256) void ksegU(const void* __restrict__ invv, int N){
  const int inv64 = g_inv64;
  int m = 0;
  const int stride = gridDim.x*blockDim.x;
  if (inv64){
    const long long* q = (const long long*)invv;
    for (int i = blockIdx.x*blockDim.x + threadIdx.x; i < N; i += stride)
      m = max(m, (int)q[i]);
  } else {
    const int* q = (const int*)invv;
    for (int i = blockIdx.x*blockDim.x + threadIdx.x; i < N; i += stride)
      m = max(m, q[i]);
  }
  #pragma unroll
  for (int off = 32; off > 0; off >>= 1) m = max(m, __shfl_xor(m, off, 64));
  if ((threadIdx.x & 63) == 0) atomicMax(&g_umax, m);
}

// sets g_U, then sniffs unq dtype
__global__ void ksniff_unq(const u32* __restrict__ w){
  __shared__ int any;
  if (threadIdx.x == 0){ g_U = (long)g_umax + 1; any = 0; }
  __syncthreads();
  const long nwords = 3L*g_U;
  for (long i = 2L*threadIdx.x + 1; i < nwords; i += 2L*blockDim.x){
    if (w[i] != 0u){ any = 1; break; }
  }
  __syncthreads();
  if (threadIdx.x == 0) g_is64 = (any == 0) ? 1 : 0;
}

__global__ void kpoolinit(float* __restrict__ out, long outSize){
  const long U = g_U;
  const long lo = 3*U;
  const long hi = (131*U < outSize) ? 131*U : outSize;
  const long i0 = (long)blockIdx.x*blockDim.x + threadIdx.x;
  const long stride = (long)gridDim.x*blockDim.x;
  for (long i = lo + i0; i < hi; i += stride) out[i] = -INFINITY;
}

__global__ void kunq(float* __restrict__ out, const void* __restrict__ unqv, long outSize){
  const long U = g_U;
  const long n = (3*U < outSize) ? 3*U : outSize;
  const long i0 = (long)blockIdx.x*blockDim.x + threadIdx.x;
  const long stride = (long)gridDim.x*blockDim.x;
  if (g_is64){
    const long long* uq = (const long long*)unqv;
    for (long i = i0; i < n; i += stride) out[i] = (float)uq[i];
  } else {
    const int* uq = (const int*)unqv;
    for (long i = i0; i < n; i += stride) out[i] = (float)uq[i];
  }
}

__global__ __launch_bounds__(256) void kstats0(const float* __restrict__ x, int N){
  __shared__ float red[4][9];
  float a[9];
  #pragma unroll
  for (int i = 0; i < 9; ++i) a[i] = 0.f;
  const int stride = gridDim.x*blockDim.x;
  for (int p = blockIdx.x*blockDim.x + threadIdx.x; p < N; p += stride){
    float v0 = x[(size_t)p*3 + 0], v1 = x[(size_t)p*3 + 1], v2 = x[(size_t)p*3 + 2];
    a[0]+=v0; a[1]+=v1; a[2]+=v2;
    a[3]+=v0*v0; a[4]+=v1*v1; a[5]+=v2*v2;
    a[6]+=v0*v1; a[7]+=v0*v2; a[8]+=v1*v2;
  }
  waveRedArr(a, 9);
  const int w = threadIdx.x >> 6, lane = threadIdx.x & 63;
  if (lane == 0){
    #pragma unroll
    for (int i = 0; i < 9; ++i) red[w][i] = a[i];
  }
  __syncthreads();
  if (threadIdx.x < 9){
    float t = 0.f;
    #pragma unroll
    for (int k = 0; k < 4; ++k) t += red[k][threadIdx.x];
    const int c = threadIdx.x;
    atomicAdd(&g_acc[(c < 3) ? (S0 + c) : (Q0 + (c - 3))], t);
  }
}

__global__ void kfin(int dim, int soff, int qoff,
                     const float* __restrict__ g, const float* __restrict__ b, float invN){
  const int j = threadIdx.x;
  if (j >= dim) return;
  const float m = g_acc[soff+j]*invN;
  const float var = fmaxf(g_acc[qoff+j]*invN - m*m, 0.f);
  const float s = g[j]*rsqrtf(var + EPS);
  g_st[soff+j] = s;
  g_st[qoff+j] = b[j] - m*s;
}

// analytic BN1 finalize (pass-1 elimination)
__global__ void kfin1(const float* __restrict__ g1, const float* __restrict__ b1bn,
                      const float* __restrict__ W1, const float* __restrict__ b1lin,
                      float invN){
  const int j = threadIdx.x;
  if (j >= 64) return;
  float m0[3], s0[3], t0[3];
  #pragma unroll
  for (int c = 0; c < 3; ++c){
    m0[c] = g_acc[S0+c]*invN;
    s0[c] = g_st[S0+c];
    t0[c] = g_st[Q0+c];
  }
  float C[3][3];
  C[0][0] = g_acc[Q0+0]*invN - m0[0]*m0[0];
  C[1][1] = g_acc[Q0+1]*invN - m0[1]*m0[1];
  C[2][2] = g_acc[Q0+2]*invN - m0[2]*m0[2];
  C[0][1] = C[1][0] = g_acc[Q0+3]*invN - m0[0]*m0[1];
  C[0][2] = C[2][0] = g_acc[Q0+4]*invN - m0[0]*m0[2];
  C[1][2] = C[2][1] = g_acc[Q0+5]*invN - m0[1]*m0[2];

  float wj[3] = {W1[0*64 + j], W1[1*64 + j], W1[2*64 + j]};
  float mean = b1lin[j];
  #pragma unroll
  for (int c = 0; c < 3; ++c) mean += (m0[c]*s0[c] + t0[c])*wj[c];
  float var = 0.f;
  #pragma unroll
  for (int a = 0; a < 3; ++a)
    #pragma unroll
    for (int b = 0; b < 3; ++b)
      var += wj[a]*s0[a]*wj[b]*s0[b]*C[a][b];
  var = fmaxf(var, 0.f);
  const float sc = g1[j]*rsqrtf(var + EPS);
  g_st[S1+j] = sc;
  g_st[Q1+j] = b1bn[j] - mean*sc;
}

// Workspace layout (bf16, TILE-MAJOR): z3 = ws[tile][256][64], z2 after z3:
//   z3 tile stride 16384 u16; z2 tile stride 8192 u16.
// Tile-major => per-chunk stores/loads are base + jj*128B immediate offsets
// (one address register instead of 16 — fixes the R14 VGPR regression).

// kpass2: layer-2 stats; WS2=1 also stores pre-BN z2 (tile-major bf16)
template<int WS2>
__global__ __launch_bounds__(256) void kpass2(
    const float* __restrict__ x,
    const float* __restrict__ W1, const float* __restrict__ b1,
    const float* __restrict__ W2, const float* __restrict__ b2,
    u16* __restrict__ z2ws, int N)
{
  __shared__ u16 h1s[64*PTS];
  __shared__ float bs[256], bq[256];
  const int tid = threadIdx.x, w = tid >> 6, lane = tid & 63;

  for (int i = tid; i < 256; i += 256){ bs[i] = 0.f; bq[i] = 0.f; }
  __syncthreads();

  const int nb = (N + PTS - 1) / PTS;
  for (int b = blockIdx.x; b < nb; b += gridDim.x){
    const int p = b*PTS + lane;
    const bool valid = p < N;
    { // bn0 + L1
      float h0[3];
      #pragma unroll
      for (int c = 0; c < 3; ++c){
        float xv = valid ? x[(size_t)p*3 + c] : 0.f;
        h0[c] = xv*g_st[S0 + c] + g_st[Q0 + c];
      }
      const int j0u = __builtin_amdgcn_readfirstlane(w*16);
      float acc[16];
      #pragma unroll
      for (int jj = 0; jj < 16; ++jj) acc[jj] = b1[j0u + jj];
      #pragma unroll
      for (int k = 0; k < 3; ++k){
        const float* Wr = W1 + k*64 + j0u;
        #pragma unroll
        for (int jj = 0; jj < 16; ++jj) acc[jj] = fmaf(h0[k], Wr[jj], acc[jj]);
      }
      emitH(acc, lane, j0u, S1, Q1, h1s);
    }
    __syncthreads();
    #pragma unroll
    for (int c = 0; c < 2; ++c){ // L2
      const int j0 = w*32 + c*16;
      float acc[16];
      chunk16<64,128>(h1s, lane, W2, b2, j0, acc);
      if constexpr (WS2){
        const int j0u = __builtin_amdgcn_readfirstlane(j0);
        u16* q = z2ws + (size_t)b*8192 + (size_t)j0u*64 + lane;
        #pragma unroll
        for (int jj = 0; jj < 16; ++jj) q[jj*64] = f2bf(acc[jj]);  // imm offsets
      }
      emitStats(acc, valid, lane, j0, bs, bq);
    }
    __syncthreads();
  }
  for (int j = tid; j < 128; j += 256){
    atomicAdd(&g_acc[S2 + j], bs[j]);
    atomicAdd(&g_acc[Q2 + j], bq[j]);
  }
}

// kpass3: layer-3 stats + z3 store. MODE: 1 = recompute L1+L2; 2 = load z2 from ws.
template<int MODE>
__global__ __launch_bounds__(256) void kpass3(
    const float* __restrict__ x,
    const float* __restrict__ W1, const float* __restrict__ b1,
    const float* __restrict__ W2, const float* __restrict__ b2,
    const float* __restrict__ W3, const float* __restrict__ b3,
    u16* __restrict__ z3ws, u16* __restrict__ z2ws, int N)
{
  constexpr int BUF_U16 = (MODE == 2) ? 8192 : 12288;
  __shared__ u16 buf[BUF_U16];
  __shared__ float bs[256], bq[256];
  u16* const h2s = buf;
  u16* const h1s = buf + ((MODE == 2) ? 0 : 8192);
  const int tid = threadIdx.x, w = tid >> 6, lane = tid & 63;

  for (int i = tid; i < 256; i += 256){ bs[i] = 0.f; bq[i] = 0.f; }
  __syncthreads();

  const int nb = (N + PTS - 1) / PTS;
  for (int b = blockIdx.x; b < nb; b += gridDim.x){
    const int p = b*PTS + lane;
    const bool valid = p < N;

    if constexpr (MODE == 2){ // load z2 tile -> bn2+relu -> h2
      const int j0u = __builtin_amdgcn_readfirstlane(w*32);
      const u16* q = z2ws + (size_t)b*8192 + (size_t)j0u*64 + lane;
      #pragma unroll
      for (int mm = 0; mm < 32; ++mm){
        const int m = j0u + mm;
        float z = bf2f(q[mm*64]);
        z = fmaxf(z*g_st[S2 + m] + g_st[Q2 + m], 0.f);
        h2s[m*PTS + lane] = f2bf(z);
      }
    } else { // recompute L1+L2
      { float h0[3];
        #pragma unroll
        for (int c = 0; c < 3; ++c){
          float xv = valid ? x[(size_t)p*3 + c] : 0.f;
          h0[c] = xv*g_st[S0 + c] + g_st[Q0 + c];
        }
        const int j0u = __builtin_amdgcn_readfirstlane(w*16);
        float acc[16];
        #pragma unroll
        for (int jj = 0; jj < 16; ++jj) acc[jj] = b1[j0u + jj];
        #pragma unroll
        for (int k = 0; k < 3; ++k){
          const float* Wr = W1 + k*64 + j0u;
          #pragma unroll
          for (int jj = 0; jj < 16; ++jj) acc[jj] = fmaf(h0[k], Wr[jj], acc[jj]);
        }
        emitH(acc, lane, j0u, S1, Q1, h1s);
      }
      __syncthreads();
      #pragma unroll
      for (int c = 0; c < 2; ++c){
        const int j0 = w*32 + c*16;
        float acc[16];
        chunk16<64,128>(h1s, lane, W2, b2, j0, acc);
        emitH(acc, lane, __builtin_amdgcn_readfirstlane(j0), S2, Q2, h2s);
      }
    }
    __syncthreads();  // h2 ready
    #pragma unroll
    for (int c = 0; c < 4; ++c){ // L3 + store + stats
      const int j0 = w*64 + c*16;
      float acc[16];
      chunk16<128,256>(h2s, lane, W3, b3, j0, acc);
      const int j0u = __builtin_amdgcn_readfirstlane(j0);
      u16* q = z3ws + (size_t)b*16384 + (size_t)j0u*64 + lane;
      #pragma unroll
      for (int jj = 0; jj < 16; ++jj) q[jj*64] = f2bf(acc[jj]);  // imm offsets
      emitStats(acc, valid, lane, j0, bs, bq);
    }
    __syncthreads();
  }
  for (int j = tid; j < 256; j += 256){
    atomicAdd(&g_acc[S3 + j], bs[j]);
    atomicAdd(&g_acc[Q3 + j], bq[j]);
  }
}

// kpass4: L4 + coalesced segment-max. MODE: 0 = full recompute (halved h3);
// 2 = load bf16 z3 tile-major from ws.
template<int MODE>
__global__ __launch_bounds__(256) void kpass4(
    const float* __restrict__ x, const void* __restrict__ unq_inv_v,
    const float* __restrict__ W1, const float* __restrict__ b1,
    const float* __restrict__ W2, const float* __restrict__ b2,
    const float* __restrict__ W3, const float* __restrict__ b3,
    const float* __restrict__ W4, const float* __restrict__ b4,
    u16* __restrict__ z3ws, float* __restrict__ out, int N, long outSize)
{
  __shared__ u16 buf[16896];   // 33.8 KB: h-tiles overlay + z4[64][Z4S]
  __shared__ int seg_s[64];
  u16* const h1s = buf + 8192;          // MODE 0
  u16* const h2s = buf;                 // MODE 0
  u16* const h3h = buf + 8192;          // MODE 0: 128-feature half tile
  u16* const h3s = buf;                 // MODE 2: full tile
  float* const z4 = (float*)buf;

  const long U = g_U;
  const int inv64 = g_inv64;
  const long loEl = 3*U;
  const long hiEl = (131*U < outSize) ? 131*U : outSize;
  const int tid = threadIdx.x, w = tid >> 6, lane = tid & 63;

  const int nb = (N + PTS - 1) / PTS;
  for (int b = blockIdx.x; b < nb; b += gridDim.x){
    const int p = b*PTS + lane;
    const bool valid = p < N;
    float accA[16], accB[16];

    if constexpr (MODE == 0){
      { float h0[3];
        #pragma unroll
        for (int c = 0; c < 3; ++c){
          float xv = valid ? x[(size_t)p*3 + c] : 0.f;
          h0[c] = xv*g_st[S0 + c] + g_st[Q0 + c];
        }
        const int j0u = __builtin_amdgcn_readfirstlane(w*16);
        float acc[16];
        #pragma unroll
        for (int jj = 0; jj < 16; ++jj) acc[jj] = b1[j0u + jj];
        #pragma unroll
        for (int k = 0; k < 3; ++k){
          const float* Wr = W1 + k*64 + j0u;
          #pragma unroll
          for (int jj = 0; jj < 16; ++jj) acc[jj] = fmaf(h0[k], Wr[jj], acc[jj]);
        }
        emitH(acc, lane, j0u, S1, Q1, h1s);
      }
      __syncthreads();
      #pragma unroll
      for (int c = 0; c < 2; ++c){
        const int j0 = w*32 + c*16;
        float acc[16];
        chunk16<64,128>(h1s, lane, W2, b2, j0, acc);
        emitH(acc, lane, __builtin_amdgcn_readfirstlane(j0), S2, Q2, h2s);
      }
      const int jA = __builtin_amdgcn_readfirstlane(w*32);
      #pragma unroll
      for (int jj = 0; jj < 16; ++jj){ accA[jj] = b4[jA + jj]; accB[jj] = b4[jA + 16 + jj]; }
      #pragma unroll
      for (int half = 0; half < 2; ++half){
        __syncthreads();
        #pragma unroll
        for (int c = 0; c < 2; ++c){
          const int j0 = half*128 + w*32 + c*16;
          float acc[16];
          chunk16<128,256>(h2s, lane, W3, b3, j0, acc);
          const int j0u = __builtin_amdgcn_readfirstlane(j0);
          const int r0  = j0u - half*128;
          #pragma unroll
          for (int jj = 0; jj < 16; ++jj){
            float z = fmaxf(acc[jj]*g_st[S3+j0u+jj] + g_st[Q3+j0u+jj], 0.f);
            h3h[(r0+jj)*PTS + lane] = f2bf(z);
          }
        }
        __syncthreads();
        chunk16_acc<128,128>(h3h, lane, W4, w*32,      half*128, accA);
        chunk16_acc<128,128>(h3h, lane, W4, w*32 + 16, half*128, accB);
      }
    } else {
      // MODE 2: load bf16 z3 tile-major, bn3+relu -> full h3
      const int j0u = __builtin_amdgcn_readfirstlane(w*64);
      const u16* q = z3ws + (size_t)b*16384 + (size_t)j0u*64 + lane;
      #pragma unroll 8
      for (int mm = 0; mm < 64; ++mm){
        const int m = j0u + mm;
        float z = bf2f(q[mm*64]);
        z = fmaxf(z*g_st[S3 + m] + g_st[Q3 + m], 0.f);
        h3s[m*PTS + lane] = f2bf(z);
      }
      __syncthreads();
      chunk16<256,128>(h3s, lane, W4, b4, w*32,      accA);
      chunk16<256,128>(h3s, lane, W4, b4, w*32 + 16, accB);
    }
    // common tail: seg, z4 staging, coalesced flush
    if (w == 0){
      long seg = -1;
      if (valid){
        if (inv64) seg = (long)((const long long*)unq_inv_v)[p];
        else       seg = (long)((const int*)unq_inv_v)[p];
      }
      seg_s[lane] = (seg >= 0 && seg < U &&
                     loEl + seg*128 + 128 <= hiEl) ? (int)seg : -1;
    }
    __syncthreads();
    {
      float4* dst = (float4*)&z4[lane*Z4S + w*32];
      dst[0] = make_float4(accA[ 0],accA[ 1],accA[ 2],accA[ 3]);
      dst[1] = make_float4(accA[ 4],accA[ 5],accA[ 6],accA[ 7]);
      dst[2] = make_float4(accA[ 8],accA[ 9],accA[10],accA[11]);
      dst[3] = make_float4(accA[12],accA[13],accA[14],accA[15]);
      dst[4] = make_float4(accB[ 0],accB[ 1],accB[ 2],accB[ 3]);
      dst[5] = make_float4(accB[ 4],accB[ 5],accB[ 6],accB[ 7]);
      dst[6] = make_float4(accB[ 8],accB[ 9],accB[10],accB[11]);
      dst[7] = make_float4(accB[12],accB[13],accB[14],accB[15]);
    }
    __syncthreads();
    #pragma unroll 4
    for (int pt2 = 0; pt2 < 64; pt2 += 2){
      const int pt = pt2 + (tid >> 7);
      const int f  = tid & 127;
      const int sg = seg_s[pt];
      if (sg >= 0)
        atomicMaxF32(out + loEl + (long)sg*128 + f, z4[pt*Z4S + f]);
    }
    __syncthreads();
  }
}

extern "C" void kernel_launch(void* const* d_in, const int* in_sizes, int n_in,
                              void* d_out, int out_size, void* d_ws, size_t ws_size,
                              hipStream_t stream)
{
  const float* x       = (const float*)d_in[0];
  const void*  unq     = d_in[2];
  const void*  unq_inv = d_in[3];
  const float* bn_g[4] = {(const float*)d_in[4], (const float*)d_in[6], (const float*)d_in[8], (const float*)d_in[10]};
  const float* bn_b[4] = {(const float*)d_in[5], (const float*)d_in[7], (const float*)d_in[9], (const float*)d_in[11]};
  const float* W1 = (const float*)d_in[12]; const float* b1 = (const float*)d_in[13];
  const float* W2 = (const float*)d_in[14]; const float* b2 = (const float*)d_in[15];
  const float* W3 = (const float*)d_in[16]; const float* b3 = (const float*)d_in[17];
  const float* W4 = (const float*)d_in[18]; const float* b4 = (const float*)d_in[19];

  const int N = in_sizes[0] / 3;
  float* out = (float*)d_out;
  const float invN = 1.0f / (float)N;
  const long outSize = (long)out_size;

  const size_t nb64 = (size_t)((N + 63) / 64);
  u16* z3ws = (u16*)d_ws;
  u16* z2ws = z3ws + nb64*16384;
  const size_t need1 = nb64*16384*sizeof(u16);          // z3: 512 MB
  const size_t need2 = nb64*(16384+8192)*sizeof(u16);   // z3+z2: 768 MB
  const int wsLevel = (ws_size >= need2) ? 2 : (ws_size >= need1) ? 1 : 0;

  kreset<<<1, 1024, 0, stream>>>();
  ksniff_inv<<<1, 1024, 0, stream>>>((const u32*)unq_inv, (long)N);
  ksegU<<<512, 256, 0, stream>>>(unq_inv, N);
  ksniff_unq<<<1, 1024, 0, stream>>>((const u32*)unq);   // also sets g_U
  kpoolinit<<<2048, 256, 0, stream>>>(out, outSize);

  kstats0<<<1024, 256, 0, stream>>>(x, N);
  kfin<<<1, 256, 0, stream>>>(3, S0, Q0, bn_g[0], bn_b[0], invN);
  kfin1<<<1, 64, 0, stream>>>(bn_g[1], bn_b[1], W1, b1, invN);

  if (wsLevel == 2) kpass2<1><<<2048, 256, 0, stream>>>(x, W1,b1,W2,b2, z2ws, N);
  else              kpass2<0><<<2048, 256, 0, stream>>>(x, W1,b1,W2,b2, z2ws, N);
  kfin<<<1, 256, 0, stream>>>(128, S2, Q2, bn_g[2], bn_b[2], invN);

  if (wsLevel == 2)      kpass3<2><<<2048, 256, 0, stream>>>(x, W1,b1,W2,b2,W3,b3, z3ws, z2ws, N);
  else if (wsLevel == 1) kpass3<1><<<1536, 256, 0, stream>>>(x, W1,b1,W2,b2,W3,b3, z3ws, z2ws, N);
  else                   kpass3<1><<<1536, 256, 0, stream>>>(x, W1,b1,W2,b2,W3,b3, z3ws, z2ws, N);
  kfin<<<1, 256, 0, stream>>>(256, S3, Q3, bn_g[3], bn_b[3], invN);

  if (wsLevel >= 1) kpass4<2><<<1024, 256, 0, stream>>>(x, unq_inv, W1,b1,W2,b2,W3,b3,W4,b4, z3ws, out, N, outSize);
  else              kpass4<0><<<1024, 256, 0, stream>>>(x, unq_inv, W1,b1,W2,b2,W3,b3,W4,b4, z3ws, out, N, outSize);

  kunq<<<2048, 256, 0, stream>>>(out, unq, outSize);
}

// Round 16
// 1553.504 us; speedup vs baseline: 2.3959x; 1.6261x over previous
//
#include <hip/hip_runtime.h>
#include <math.h>

typedef unsigned int u32;
typedef unsigned short u16;

#define EPS 1e-5f
#define PTS 64

#define S0 0
#define Q0 16
#define S1 32
#define Q1 96
#define S2 160
#define Q2 288
#define S3 416
#define Q3 672

#define Z4S 132

typedef __attribute__((ext_vector_type(8))) short v8s;
typedef __attribute__((ext_vector_type(4))) float v4f;
typedef __attribute__((ext_vector_type(2))) unsigned int v2u;

#define MFMA(a,b,c) __builtin_amdgcn_mfma_f32_16x16x32_bf16(a,b,c,0,0,0)

// W-fragment (A-operand, W^T) hi/lo buffers, u16 offsets
#define W2H 0
#define W2L 8192
#define W3H 16384
#define W3L 49152
#define W4H 81920
#define W4L 114688
__device__ __align__(16) u16 g_wfrag[147456];

__device__ float g_acc[1024];
__device__ float g_st[1024];
__device__ int   g_is64;
__device__ int   g_inv64;
__device__ int   g_umax;
__device__ long  g_U;

__device__ __forceinline__ float bf2f(u16 b){ return __uint_as_float(((u32)b) << 16); }
__device__ __forceinline__ u16 f2bf(float f){
  u32 u = __float_as_uint(f);
  return (u16)((u + 0x7fffu + ((u >> 16) & 1u)) >> 16);  // RNE
}

__device__ __forceinline__ void atomicMaxF32(float* addr, float v){
  if (v == 0.f) v = 0.f;
  if (v >= 0.f) atomicMax((int*)addr, __float_as_int(v));
  else          atomicMin((u32*)addr, __float_as_uint(v));
}

__device__ __forceinline__ void waveRedArr(float* v, int n){
  #pragma unroll
  for (int off = 32; off > 0; off >>= 1)
    for (int i = 0; i < n; ++i) v[i] += __shfl_xor(v[i], off, 64);
}

template<int FIN, int FOUT>
__device__ __forceinline__ void chunk16(const u16* hsrc, int lane,
    const float* __restrict__ W, const float* __restrict__ bias,
    int j0, float acc[16])
{
  const int j0u = __builtin_amdgcn_readfirstlane(j0);
  #pragma unroll
  for (int jj = 0; jj < 16; ++jj) acc[jj] = bias[j0u + jj];
  #pragma unroll 4
  for (int k = 0; k < FIN; ++k){
    const float hk = bf2f(hsrc[k*PTS + lane]);
    const float* Wr = W + (long)k*FOUT + j0u;
    #pragma unroll
    for (int jj = 0; jj < 16; ++jj) acc[jj] = fmaf(hk, Wr[jj], acc[jj]);
  }
}

template<int FIN, int FOUT>
__device__ __forceinline__ void chunk16_acc(const u16* hsrc, int lane,
    const float* __restrict__ W, int j0, int k0, float acc[16])
{
  const int j0u = __builtin_amdgcn_readfirstlane(j0);
  #pragma unroll 4
  for (int k = 0; k < FIN; ++k){
    const float hk = bf2f(hsrc[k*PTS + lane]);
    const float* Wr = W + (long)(k0 + k)*FOUT + j0u;
    #pragma unroll
    for (int jj = 0; jj < 16; ++jj) acc[jj] = fmaf(hk, Wr[jj], acc[jj]);
  }
}

__device__ __forceinline__ void emitStats(float acc[16], bool valid, int lane, int j0,
                                          float* bs, float* bq){
  #pragma unroll
  for (int jj = 0; jj < 16; ++jj){
    float v = valid ? acc[jj] : 0.f;
    float sq[2] = {v, v*v};
    waveRedArr(sq, 2);
    if (lane == 0){ atomicAdd(&bs[j0+jj], sq[0]); atomicAdd(&bq[j0+jj], sq[1]); }
  }
}
__device__ __forceinline__ void emitH(float acc[16], int lane, int j0u, int soff, int qoff, u16* hdst){
  #pragma unroll
  for (int jj = 0; jj < 16; ++jj){
    float z = fmaxf(acc[jj]*g_st[soff+j0u+jj] + g_st[qoff+j0u+jj], 0.f);
    hdst[(j0u+jj)*PTS + lane] = f2bf(z);
  }
}

__global__ void kreset(){
  if (threadIdx.x == 0) g_umax = 0;
  for (int i = threadIdx.x; i < 1024; i += blockDim.x) g_acc[i] = 0.f;
}

__global__ void ksniff_inv(const u32* __restrict__ w, long nwords){
  __shared__ int any;
  if (threadIdx.x == 0) any = 0;
  __syncthreads();
  for (long i = 2L*threadIdx.x + 1; i < nwords; i += 2L*blockDim.x){
    if (w[i] != 0u){ any = 1; break; }
  }
  __syncthreads();
  if (threadIdx.x == 0) g_inv64 = (any == 0) ? 1 : 0;
}

__global__ __launch_bounds__(256) void ksegU(const void* __restrict__ invv, int N){
  const int inv64 = g_inv64;
  int m = 0;
  const int stride = gridDim.x*blockDim.x;
  if (inv64){
    const long long* q = (const long long*)invv;
    for (int i = blockIdx.x*blockDim.x + threadIdx.x; i < N; i += stride)
      m = max(m, (int)q[i]);
  } else {
    const int* q = (const int*)invv;
    for (int i = blockIdx.x*blockDim.x + threadIdx.x; i < N; i += stride)
      m = max(m, q[i]);
  }
  #pragma unroll
  for (int off = 32; off > 0; off >>= 1) m = max(m, __shfl_xor(m, off, 64));
  if ((threadIdx.x & 63) == 0) atomicMax(&g_umax, m);
}

__global__ void ksniff_unq(const u32* __restrict__ w){
  __shared__ int any;
  if (threadIdx.x == 0){ g_U = (long)g_umax + 1; any = 0; }
  __syncthreads();
  const long nwords = 3L*g_U;
  for (long i = 2L*threadIdx.x + 1; i < nwords; i += 2L*blockDim.x){
    if (w[i] != 0u){ any = 1; break; }
  }
  __syncthreads();
  if (threadIdx.x == 0) g_is64 = (any == 0) ? 1 : 0;
}

__global__ void kpoolinit(float* __restrict__ out, long outSize){
  const long U = g_U;
  const long lo = 3*U;
  const long hi = (131*U < outSize) ? 131*U : outSize;
  const long i0 = (long)blockIdx.x*blockDim.x + threadIdx.x;
  const long stride = (long)gridDim.x*blockDim.x;
  for (long i = lo + i0; i < hi; i += stride) out[i] = -INFINITY;
}

__global__ void kunq(float* __restrict__ out, const void* __restrict__ unqv, long outSize){
  const long U = g_U;
  const long n = (3*U < outSize) ? 3*U : outSize;
  const long i0 = (long)blockIdx.x*blockDim.x + threadIdx.x;
  const long stride = (long)gridDim.x*blockDim.x;
  if (g_is64){
    const long long* uq = (const long long*)unqv;
    for (long i = i0; i < n; i += stride) out[i] = (float)uq[i];
  } else {
    const int* uq = (const int*)unqv;
    for (long i = i0; i < n; i += stride) out[i] = (float)uq[i];
  }
}

__global__ __launch_bounds__(256) void kstats0(const float* __restrict__ x, int N){
  __shared__ float red[4][9];
  float a[9];
  #pragma unroll
  for (int i = 0; i < 9; ++i) a[i] = 0.f;
  const int stride = gridDim.x*blockDim.x;
  for (int p = blockIdx.x*blockDim.x + threadIdx.x; p < N; p += stride){
    float v0 = x[(size_t)p*3 + 0], v1 = x[(size_t)p*3 + 1], v2 = x[(size_t)p*3 + 2];
    a[0]+=v0; a[1]+=v1; a[2]+=v2;
    a[3]+=v0*v0; a[4]+=v1*v1; a[5]+=v2*v2;
    a[6]+=v0*v1; a[7]+=v0*v2; a[8]+=v1*v2;
  }
  waveRedArr(a, 9);
  const int w = threadIdx.x >> 6, lane = threadIdx.x & 63;
  if (lane == 0){
    #pragma unroll
    for (int i = 0; i < 9; ++i) red[w][i] = a[i];
  }
  __syncthreads();
  if (threadIdx.x < 9){
    float t = 0.f;
    #pragma unroll
    for (int k = 0; k < 4; ++k) t += red[k][threadIdx.x];
    const int c = threadIdx.x;
    atomicAdd(&g_acc[(c < 3) ? (S0 + c) : (Q0 + (c - 3))], t);
  }
}

__global__ void kfin(int dim, int soff, int qoff,
                     const float* __restrict__ g, const float* __restrict__ b, float invN){
  const int j = threadIdx.x;
  if (j >= dim) return;
  const float m = g_acc[soff+j]*invN;
  const float var = fmaxf(g_acc[qoff+j]*invN - m*m, 0.f);
  const float s = g[j]*rsqrtf(var + EPS);
  g_st[soff+j] = s;
  g_st[qoff+j] = b[j] - m*s;
}

__global__ void kfin1(const float* __restrict__ g1, const float* __restrict__ b1bn,
                      const float* __restrict__ W1, const float* __restrict__ b1lin,
                      float invN){
  const int j = threadIdx.x;
  if (j >= 64) return;
  float m0[3], s0[3], t0[3];
  #pragma unroll
  for (int c = 0; c < 3; ++c){
    m0[c] = g_acc[S0+c]*invN;
    s0[c] = g_st[S0+c];
    t0[c] = g_st[Q0+c];
  }
  float C[3][3];
  C[0][0] = g_acc[Q0+0]*invN - m0[0]*m0[0];
  C[1][1] = g_acc[Q0+1]*invN - m0[1]*m0[1];
  C[2][2] = g_acc[Q0+2]*invN - m0[2]*m0[2];
  C[0][1] = C[1][0] = g_acc[Q0+3]*invN - m0[0]*m0[1];
  C[0][2] = C[2][0] = g_acc[Q0+4]*invN - m0[0]*m0[2];
  C[1][2] = C[2][1] = g_acc[Q0+5]*invN - m0[1]*m0[2];

  float wj[3] = {W1[0*64 + j], W1[1*64 + j], W1[2*64 + j]};
  float mean = b1lin[j];
  #pragma unroll
  for (int c = 0; c < 3; ++c) mean += (m0[c]*s0[c] + t0[c])*wj[c];
  float var = 0.f;
  #pragma unroll
  for (int a = 0; a < 3; ++a)
    #pragma unroll
    for (int b = 0; b < 3; ++b)
      var += wj[a]*s0[a]*wj[b]*s0[b]*C[a][b];
  var = fmaxf(var, 0.f);
  const float sc = g1[j]*rsqrtf(var + EPS);
  g_st[S1+j] = sc;
  g_st[Q1+j] = b1bn[j] - mean*sc;
}

// ================= MFMA path (wsLevel 2) =================
// A-frag (W^T): lane holds row(feat)=l&15, k=kb*32+(l>>4)*8+jj.
// B-frag (h):   lane holds col(pt)=l&15,  k=kb*32+(l>>4)*8+jj.
// D:            lane holds col(pt)=l&15,  row(feat)=fb*16+(l>>4)*4+r  [m89]

__global__ void kprep(const float* __restrict__ W2, const float* __restrict__ W3,
                      const float* __restrict__ W4){
  int t = blockIdx.x*blockDim.x + threadIdx.x;
  int frag = t >> 6, lane = t & 63;
  if (frag >= 144) return;
  const float* W; int F, fb, kb; u16 *hi, *lo;
  if (frag < 16){
    fb = frag >> 1; kb = frag & 1; W = W2; F = 128;
    size_t o = (size_t)((fb*2 + kb)*64 + lane)*8;
    hi = g_wfrag + W2H + o; lo = g_wfrag + W2L + o;
  } else if (frag < 80){
    int f = frag - 16; fb = f >> 2; kb = f & 3; W = W3; F = 256;
    size_t o = (size_t)((fb*4 + kb)*64 + lane)*8;
    hi = g_wfrag + W3H + o; lo = g_wfrag + W3L + o;
  } else {
    int f = frag - 80; fb = f >> 3; kb = f & 7; W = W4; F = 128;
    size_t o = (size_t)((fb*8 + kb)*64 + lane)*8;
    hi = g_wfrag + W4H + o; lo = g_wfrag + W4L + o;
  }
  const int feat = fb*16 + (lane & 15);
  const int k0 = kb*32 + (lane >> 4)*8;
  #pragma unroll
  for (int jj = 0; jj < 8; ++jj){
    float wv = W[(size_t)(k0 + jj)*F + feat];
    u16 h = f2bf(wv);
    hi[jj] = h;
    lo[jj] = f2bf(wv - bf2f(h));
  }
}

// kpass2m: scalar L1 -> h1 B-frag; MFMA L2; reg-stats; z2 B-frag to ws
__global__ __launch_bounds__(256) void kpass2m(
    const float* __restrict__ x,
    const float* __restrict__ W1, const float* __restrict__ b1,
    const float* __restrict__ b2, u16* __restrict__ z2ws, int N)
{
  __shared__ __align__(16) u16 h1f[4096];   // [kb(2)][pb(4)][64][8]
  __shared__ __align__(16) u16 z2f[8192];   // [kb2(4)][pb(4)][64][8]
  const int tid = threadIdx.x, w = tid >> 6, lane = tid & 63;
  const int g = lane >> 4, p15 = lane & 15;

  float s2[2][4], q2[2][4];
  #pragma unroll
  for (int f = 0; f < 2; ++f)
    #pragma unroll
    for (int r = 0; r < 4; ++r){ s2[f][r] = 0.f; q2[f][r] = 0.f; }

  const int j0u = __builtin_amdgcn_readfirstlane(w*16);
  const int nb = (N + 63) >> 6;
  for (int b = blockIdx.x; b < nb; b += gridDim.x){
    const int p = b*64 + lane;
    const bool valid = p < N;
    { // L1 scalar + bn1relu -> h1f
      float h0[3];
      #pragma unroll
      for (int c = 0; c < 3; ++c){
        float xv = valid ? x[(size_t)p*3 + c] : 0.f;
        h0[c] = xv*g_st[S0 + c] + g_st[Q0 + c];
      }
      float acc[16];
      #pragma unroll
      for (int jj = 0; jj < 16; ++jj) acc[jj] = b1[j0u + jj];
      #pragma unroll
      for (int k = 0; k < 3; ++k){
        const float* Wr = W1 + k*64 + j0u;
        #pragma unroll
        for (int jj = 0; jj < 16; ++jj) acc[jj] = fmaf(h0[k], Wr[jj], acc[jj]);
      }
      u16 hb[16];
      #pragma unroll
      for (int jj = 0; jj < 16; ++jj)
        hb[jj] = f2bf(fmaxf(acc[jj]*g_st[S1+j0u+jj] + g_st[Q1+j0u+jj], 0.f));
      const int kb = w >> 1;
      const int lA = ((2*w) & 3)*16 + p15;
      union { v8s v; u32 u[4]; } pa, pbk;
      #pragma unroll
      for (int q = 0; q < 4; ++q){
        pa.u[q]  = (u32)hb[2*q]     | ((u32)hb[2*q+1] << 16);
        pbk.u[q] = (u32)hb[8+2*q]   | ((u32)hb[8+2*q+1] << 16);
      }
      *(v8s*)(h1f + ((kb*4 + g)*64 + lA     )*8) = pa.v;
      *(v8s*)(h1f + ((kb*4 + g)*64 + lA + 16)*8) = pbk.v;
    }
    __syncthreads();
    #pragma unroll
    for (int f = 0; f < 2; ++f){
      const int fb = w*2 + f;
      const v4f bias = *(const v4f*)(b2 + fb*16 + g*4);
      v4f acc[4];
      #pragma unroll
      for (int pb = 0; pb < 4; ++pb) acc[pb] = bias;
      #pragma unroll
      for (int kb = 0; kb < 2; ++kb){
        const v8s Ah = *(const v8s*)(g_wfrag + W2H + (size_t)((fb*2+kb)*64 + lane)*8);
        const v8s Al = *(const v8s*)(g_wfrag + W2L + (size_t)((fb*2+kb)*64 + lane)*8);
        #pragma unroll
        for (int pb = 0; pb < 4; ++pb){
          const v8s B = *(const v8s*)(h1f + ((kb*4 + pb)*64 + lane)*8);
          acc[pb] = MFMA(Ah, B, acc[pb]);
          acc[pb] = MFMA(Al, B, acc[pb]);
        }
      }
      #pragma unroll
      for (int pb = 0; pb < 4; ++pb){
        const bool pv = (b*64 + pb*16 + p15) < N;
        u16 zb[4];
        #pragma unroll
        for (int r = 0; r < 4; ++r){
          float v = pv ? acc[pb][r] : 0.f;
          s2[f][r] += v; q2[f][r] += v*v;
          zb[r] = f2bf(acc[pb][r]);
        }
        const int kb2 = fb >> 1;
        const int lp = ((2*fb + (g >> 1)) & 3)*16 + p15;
        v2u dv; dv[0] = (u32)zb[0] | ((u32)zb[1] << 16);
        dv[1] = (u32)zb[2] | ((u32)zb[3] << 16);
        *(v2u*)(z2f + ((kb2*4 + pb)*64 + lp)*8 + 4*(g & 1)) = dv;
      }
    }
    __syncthreads();
    { // copy z2f -> ws
      u16* dst = z2ws + (size_t)b*8192;
      #pragma unroll
      for (int i = 0; i < 4; ++i){
        const int idx = (i*256 + tid)*8;
        *(v8s*)(dst + idx) = *(const v8s*)(z2f + idx);
      }
    }
    __syncthreads();
  }
  #pragma unroll
  for (int f = 0; f < 2; ++f)
    #pragma unroll
    for (int r = 0; r < 4; ++r){
      float s = s2[f][r], q = q2[f][r];
      #pragma unroll
      for (int off = 1; off < 16; off <<= 1){
        s += __shfl_xor(s, off, 64); q += __shfl_xor(q, off, 64);
      }
      if (p15 == 0){
        const int feat = (w*2 + f)*16 + g*4 + r;
        atomicAdd(&g_acc[S2 + feat], s);
        atomicAdd(&g_acc[Q2 + feat], q);
      }
    }
}

// kpass3m: z2 frags -> bn2relu -> h2 B-frag; MFMA L3; reg-stats; z3 B-frag to ws
__global__ __launch_bounds__(256) void kpass3m(
    const u16* __restrict__ z2ws, const float* __restrict__ b3,
    u16* __restrict__ z3ws, int N)
{
  __shared__ __align__(16) u16 h2f[8192];    // [kb(4)][pb(4)][64][8]
  __shared__ __align__(16) u16 z3f[16384];   // [kb3(8)][pb(4)][64][8]
  const int tid = threadIdx.x, w = tid >> 6, lane = tid & 63;
  const int g = lane >> 4, p15 = lane & 15;

  const int k0 = w*32 + g*8;
  const v4f sA = *(const v4f*)(g_st + S2 + k0);
  const v4f sB = *(const v4f*)(g_st + S2 + k0 + 4);
  const v4f tA = *(const v4f*)(g_st + Q2 + k0);
  const v4f tB = *(const v4f*)(g_st + Q2 + k0 + 4);

  float s3[4][4], q3[4][4];
  #pragma unroll
  for (int i = 0; i < 4; ++i)
    #pragma unroll
    for (int r = 0; r < 4; ++r){ s3[i][r] = 0.f; q3[i][r] = 0.f; }

  const int nb = (N + 63) >> 6;
  for (int b = blockIdx.x; b < nb; b += gridDim.x){
    #pragma unroll
    for (int pb = 0; pb < 4; ++pb){
      union { v8s v; u32 u[4]; } in, outv;
      in.v = *(const v8s*)(z2ws + (size_t)b*8192 + ((w*4 + pb)*64 + lane)*8);
      #pragma unroll
      for (int q = 0; q < 4; ++q){
        const int e = q*2;
        float z0 = bf2f((u16)(in.u[q] & 0xFFFFu));
        float z1 = bf2f((u16)(in.u[q] >> 16));
        const float sc0 = (e   < 4) ? sA[e]   : sB[e-4];
        const float sh0 = (e   < 4) ? tA[e]   : tB[e-4];
        const float sc1 = (e+1 < 4) ? sA[e+1] : sB[e-3];
        const float sh1 = (e+1 < 4) ? tA[e+1] : tB[e-3];
        z0 = fmaxf(fmaf(z0, sc0, sh0), 0.f);
        z1 = fmaxf(fmaf(z1, sc1, sh1), 0.f);
        outv.u[q] = (u32)f2bf(z0) | ((u32)f2bf(z1) << 16);
      }
      *(v8s*)(h2f + ((w*4 + pb)*64 + lane)*8) = outv.v;
    }
    __syncthreads();
    #pragma unroll
    for (int i = 0; i < 4; ++i){
      const int fb = w*4 + i;
      const v4f bias = *(const v4f*)(b3 + fb*16 + g*4);
      v4f acc[4];
      #pragma unroll
      for (int pb = 0; pb < 4; ++pb) acc[pb] = bias;
      #pragma unroll
      for (int kb = 0; kb < 4; ++kb){
        const v8s Ah = *(const v8s*)(g_wfrag + W3H + (size_t)((fb*4+kb)*64 + lane)*8);
        const v8s Al = *(const v8s*)(g_wfrag + W3L + (size_t)((fb*4+kb)*64 + lane)*8);
        #pragma unroll
        for (int pb = 0; pb < 4; ++pb){
          const v8s B = *(const v8s*)(h2f + ((kb*4 + pb)*64 + lane)*8);
          acc[pb] = MFMA(Ah, B, acc[pb]);
          acc[pb] = MFMA(Al, B, acc[pb]);
        }
      }
      #pragma unroll
      for (int pb = 0; pb < 4; ++pb){
        const bool pv = (b*64 + pb*16 + p15) < N;
        u16 zb[4];
        #pragma unroll
        for (int r = 0; r < 4; ++r){
          float v = pv ? acc[pb][r] : 0.f;
          s3[i][r] += v; q3[i][r] += v*v;
          zb[r] = f2bf(acc[pb][r]);
        }
        const int kb3 = fb >> 1;
        const int lp = ((2*fb + (g >> 1)) & 3)*16 + p15;
        v2u dv; dv[0] = (u32)zb[0] | ((u32)zb[1] << 16);
        dv[1] = (u32)zb[2] | ((u32)zb[3] << 16);
        *(v2u*)(z3f + ((kb3*4 + pb)*64 + lp)*8 + 4*(g & 1)) = dv;
      }
    }
    __syncthreads();
    {
      u16* dst = z3ws + (size_t)b*16384;
      #pragma unroll
      for (int i2 = 0; i2 < 8; ++i2){
        const int idx = (i2*256 + tid)*8;
        *(v8s*)(dst + idx) = *(const v8s*)(z3f + idx);
      }
    }
    __syncthreads();
  }
  #pragma unroll
  for (int i = 0; i < 4; ++i)
    #pragma unroll
    for (int r = 0; r < 4; ++r){
      float s = s3[i][r], q = q3[i][r];
      #pragma unroll
      for (int off = 1; off < 16; off <<= 1){
        s += __shfl_xor(s, off, 64); q += __shfl_xor(q, off, 64);
      }
      if (p15 == 0){
        const int feat = (w*4 + i)*16 + g*4 + r;
        atomicAdd(&g_acc[S3 + feat], s);
        atomicAdd(&g_acc[Q3 + feat], q);
      }
    }
}

// kpass4m: z3 frags -> bn3relu -> h3 B-frag; MFMA L4; coalesced segment-max
__global__ __launch_bounds__(256) void kpass4m(
    const void* __restrict__ unq_inv_v, const float* __restrict__ b4,
    const u16* __restrict__ z3ws, float* __restrict__ out, int N, long outSize)
{
  __shared__ __align__(16) u16 buf[16896];   // h3f[16384] overlaid by z4 f32[64][132]
  __shared__ int seg_s[64];
  u16* const h3f = buf;
  float* const z4 = (float*)buf;

  const long U = g_U;
  const int inv64 = g_inv64;
  const long loEl = 3*U;
  const long hiEl = (131*U < outSize) ? 131*U : outSize;
  const int tid = threadIdx.x, w = tid >> 6, lane = tid & 63;
  const int g = lane >> 4, p15 = lane & 15;

  const int k0a = w*64 + g*8;
  const v4f sA0 = *(const v4f*)(g_st + S3 + k0a);
  const v4f sA1 = *(const v4f*)(g_st + S3 + k0a + 4);
  const v4f tA0 = *(const v4f*)(g_st + Q3 + k0a);
  const v4f tA1 = *(const v4f*)(g_st + Q3 + k0a + 4);
  const v4f sB0 = *(const v4f*)(g_st + S3 + k0a + 32);
  const v4f sB1 = *(const v4f*)(g_st + S3 + k0a + 36);
  const v4f tB0 = *(const v4f*)(g_st + Q3 + k0a + 32);
  const v4f tB1 = *(const v4f*)(g_st + Q3 + k0a + 36);

  const int nb = (N + 63) >> 6;
  for (int b = blockIdx.x; b < nb; b += gridDim.x){
    const int p = b*64 + lane;
    const bool valid = p < N;

    #pragma unroll
    for (int kk = 0; kk < 2; ++kk){
      const int kb3 = 2*w + kk;
      #pragma unroll
      for (int pb = 0; pb < 4; ++pb){
        union { v8s v; u32 u[4]; } in, outv;
        in.v = *(const v8s*)(z3ws + (size_t)b*16384 + ((kb3*4 + pb)*64 + lane)*8);
        #pragma unroll
        for (int q = 0; q < 4; ++q){
          const int e = q*2;
          float z0 = bf2f((u16)(in.u[q] & 0xFFFFu));
          float z1 = bf2f((u16)(in.u[q] >> 16));
          const float sc0 = kk ? ((e   < 4) ? sB0[e]   : sB1[e-4]) : ((e   < 4) ? sA0[e]   : sA1[e-4]);
          const float sh0 = kk ? ((e   < 4) ? tB0[e]   : tB1[e-4]) : ((e   < 4) ? tA0[e]   : tA1[e-4]);
          const float sc1 = kk ? ((e+1 < 4) ? sB0[e+1] : sB1[e-3]) : ((e+1 < 4) ? sA0[e+1] : sA1[e-3]);
          const float sh1 = kk ? ((e+1 < 4) ? tB0[e+1] : tB1[e-3]) : ((e+1 < 4) ? tA0[e+1] : tA1[e-3]);
          z0 = fmaxf(fmaf(z0, sc0, sh0), 0.f);
          z1 = fmaxf(fmaf(z1, sc1, sh1), 0.f);
          outv.u[q] = (u32)f2bf(z0) | ((u32)f2bf(z1) << 16);
        }
        *(v8s*)(h3f + ((kb3*4 + pb)*64 + lane)*8) = outv.v;
      }
    }
    if (w == 0){
      long seg = -1;
      if (valid){
        if (inv64) seg = (long)((const long long*)unq_inv_v)[p];
        else       seg = (long)((const int*)unq_inv_v)[p];
      }
      seg_s[lane] = (seg >= 0 && seg < U &&
                     loEl + seg*128 + 128 <= hiEl) ? (int)seg : -1;
    }
    __syncthreads();   // h3f ready; seg ready

    v4f acc[2][4];
    #pragma unroll
    for (int f = 0; f < 2; ++f){
      const int fb = w*2 + f;
      const v4f bias = *(const v4f*)(b4 + fb*16 + g*4);
      #pragma unroll
      for (int pb = 0; pb < 4; ++pb) acc[f][pb] = bias;
      #pragma unroll
      for (int kb = 0; kb < 8; ++kb){
        const v8s Ah = *(const v8s*)(g_wfrag + W4H + (size_t)((fb*8+kb)*64 + lane)*8);
        const v8s Al = *(const v8s*)(g_wfrag + W4L + (size_t)((fb*8+kb)*64 + lane)*8);
        #pragma unroll
        for (int pb = 0; pb < 4; ++pb){
          const v8s B = *(const v8s*)(h3f + ((kb*4 + pb)*64 + lane)*8);
          acc[f][pb] = MFMA(Ah, B, acc[f][pb]);
          acc[f][pb] = MFMA(Al, B, acc[f][pb]);
        }
      }
    }
    __syncthreads();   // all h3f reads done -> z4 overlay free
    #pragma unroll
    for (int f = 0; f < 2; ++f){
      const int fb = w*2 + f;
      #pragma unroll
      for (int pb = 0; pb < 4; ++pb)
        *(v4f*)(z4 + (pb*16 + p15)*Z4S + fb*16 + g*4) = acc[f][pb];
    }
    __syncthreads();   // z4 complete
    #pragma unroll 4
    for (int pt2 = 0; pt2 < 64; pt2 += 2){
      const int pt = pt2 + (tid >> 7);
      const int fI = tid & 127;
      const int sg = seg_s[pt];
      if (sg >= 0)
        atomicMaxF32(out + loEl + (long)sg*128 + fI, z4[pt*Z4S + fI]);
    }
    __syncthreads();
  }
}

// ================= scalar fallback (wsLevel < 2), from R15 =================
template<int WS2>
__global__ __launch_bounds__(256) void kpass2(
    const float* __restrict__ x,
    const float* __restrict__ W1, const float* __restrict__ b1,
    const float* __restrict__ W2, const float* __restrict__ b2,
    u16* __restrict__ z2ws, int N)
{
  __shared__ u16 h1s[64*PTS];
  __shared__ float bs[256], bq[256];
  const int tid = threadIdx.x, w = tid >> 6, lane = tid & 63;
  for (int i = tid; i < 256; i += 256){ bs[i] = 0.f; bq[i] = 0.f; }
  __syncthreads();
  const int nb = (N + PTS - 1) / PTS;
  for (int b = blockIdx.x; b < nb; b += gridDim.x){
    const int p = b*PTS + lane;
    const bool valid = p < N;
    {
      float h0[3];
      #pragma unroll
      for (int c = 0; c < 3; ++c){
        float xv = valid ? x[(size_t)p*3 + c] : 0.f;
        h0[c] = xv*g_st[S0 + c] + g_st[Q0 + c];
      }
      const int j0u = __builtin_amdgcn_readfirstlane(w*16);
      float acc[16];
      #pragma unroll
      for (int jj = 0; jj < 16; ++jj) acc[jj] = b1[j0u + jj];
      #pragma unroll
      for (int k = 0; k < 3; ++k){
        const float* Wr = W1 + k*64 + j0u;
        #pragma unroll
        for (int jj = 0; jj < 16; ++jj) acc[jj] = fmaf(h0[k], Wr[jj], acc[jj]);
      }
      emitH(acc, lane, j0u, S1, Q1, h1s);
    }
    __syncthreads();
    #pragma unroll
    for (int c = 0; c < 2; ++c){
      const int j0 = w*32 + c*16;
      float acc[16];
      chunk16<64,128>(h1s, lane, W2, b2, j0, acc);
      if constexpr (WS2){
        const int j0u = __builtin_amdgcn_readfirstlane(j0);
        u16* q = z2ws + (size_t)b*8192 + (size_t)j0u*64 + lane;
        #pragma unroll
        for (int jj = 0; jj < 16; ++jj) q[jj*64] = f2bf(acc[jj]);
      }
      emitStats(acc, valid, lane, j0, bs, bq);
    }
    __syncthreads();
  }
  for (int j = tid; j < 128; j += 256){
    atomicAdd(&g_acc[S2 + j], bs[j]);
    atomicAdd(&g_acc[Q2 + j], bq[j]);
  }
}

// MODE: 0 recompute no-store; 1 recompute + z3 store (old tile-major)
template<int MODE>
__global__ __launch_bounds__(256) void kpass3(
    const float* __restrict__ x,
    const float* __restrict__ W1, const float* __restrict__ b1,
    const float* __restrict__ W2, const float* __restrict__ b2,
    const float* __restrict__ W3, const float* __restrict__ b3,
    u16* __restrict__ z3ws, int N)
{
  __shared__ u16 buf[12288];
  __shared__ float bs[256], bq[256];
  u16* const h2s = buf;
  u16* const h1s = buf + 8192;
  const int tid = threadIdx.x, w = tid >> 6, lane = tid & 63;
  for (int i = tid; i < 256; i += 256){ bs[i] = 0.f; bq[i] = 0.f; }
  __syncthreads();
  const int nb = (N + PTS - 1) / PTS;
  for (int b = blockIdx.x; b < nb; b += gridDim.x){
    const int p = b*PTS + lane;
    const bool valid = p < N;
    {
      float h0[3];
      #pragma unroll
      for (int c = 0; c < 3; ++c){
        float xv = valid ? x[(size_t)p*3 + c] : 0.f;
        h0[c] = xv*g_st[S0 + c] + g_st[Q0 + c];
      }
      const int j0u = __builtin_amdgcn_readfirstlane(w*16);
      float acc[16];
      #pragma unroll
      for (int jj = 0; jj < 16; ++jj) acc[jj] = b1[j0u + jj];
      #pragma unroll
      for (int k = 0; k < 3; ++k){
        const float* Wr = W1 + k*64 + j0u;
        #pragma unroll
        for (int jj = 0; jj < 16; ++jj) acc[jj] = fmaf(h0[k], Wr[jj], acc[jj]);
      }
      emitH(acc, lane, j0u, S1, Q1, h1s);
    }
    __syncthreads();
    #pragma unroll
    for (int c = 0; c < 2; ++c){
      const int j0 = w*32 + c*16;
      float acc[16];
      chunk16<64,128>(h1s, lane, W2, b2, j0, acc);
      emitH(acc, lane, __builtin_amdgcn_readfirstlane(j0), S2, Q2, h2s);
    }
    __syncthreads();
    #pragma unroll
    for (int c = 0; c < 4; ++c){
      const int j0 = w*64 + c*16;
      float acc[16];
      chunk16<128,256>(h2s, lane, W3, b3, j0, acc);
      if constexpr (MODE == 1){
        const int j0u = __builtin_amdgcn_readfirstlane(j0);
        u16* q = z3ws + (size_t)b*16384 + (size_t)j0u*64 + lane;
        #pragma unroll
        for (int jj = 0; jj < 16; ++jj) q[jj*64] = f2bf(acc[jj]);
      }
      emitStats(acc, valid, lane, j0, bs, bq);
    }
    __syncthreads();
  }
  for (int j = tid; j < 256; j += 256){
    atomicAdd(&g_acc[S3 + j], bs[j]);
    atomicAdd(&g_acc[Q3 + j], bq[j]);
  }
}

template<int MODE>  // 0 full recompute; 2 load old tile-major z3
__global__ __launch_bounds__(256) void kpass4(
    const float* __restrict__ x, const void* __restrict__ unq_inv_v,
    const float* __restrict__ W1, const float* __restrict__ b1,
    const float* __restrict__ W2, const float* __restrict__ b2,
    const float* __restrict__ W3, const float* __restrict__ b3,
    const float* __restrict__ W4, const float* __restrict__ b4,
    u16* __restrict__ z3ws, float* __restrict__ out, int N, long outSize)
{
  __shared__ u16 buf[16896];
  __shared__ int seg_s[64];
  u16* const h1s = buf + 8192;
  u16* const h2s = buf;
  u16* const h3h = buf + 8192;
  u16* const h3s = buf;
  float* const z4 = (float*)buf;
  const long U = g_U;
  const int inv64 = g_inv64;
  const long loEl = 3*U;
  const long hiEl = (131*U < outSize) ? 131*U : outSize;
  const int tid = threadIdx.x, w = tid >> 6, lane = tid & 63;
  const int nb = (N + PTS - 1) / PTS;
  for (int b = blockIdx.x; b < nb; b += gridDim.x){
    const int p = b*PTS + lane;
    const bool valid = p < N;
    float accA[16], accB[16];
    if constexpr (MODE == 0){
      {
        float h0[3];
        #pragma unroll
        for (int c = 0; c < 3; ++c){
          float xv = valid ? x[(size_t)p*3 + c] : 0.f;
          h0[c] = xv*g_st[S0 + c] + g_st[Q0 + c];
        }
        const int j0u = __builtin_amdgcn_readfirstlane(w*16);
        float acc[16];
        #pragma unroll
        for (int jj = 0; jj < 16; ++jj) acc[jj] = b1[j0u + jj];
        #pragma unroll
        for (int k = 0; k < 3; ++k){
          const float* Wr = W1 + k*64 + j0u;
          #pragma unroll
          for (int jj = 0; jj < 16; ++jj) acc[jj] = fmaf(h0[k], Wr[jj], acc[jj]);
        }
        emitH(acc, lane, j0u, S1, Q1, h1s);
      }
      __syncthreads();
      #pragma unroll
      for (int c = 0; c < 2; ++c){
        const int j0 = w*32 + c*16;
        float acc[16];
        chunk16<64,128>(h1s, lane, W2, b2, j0, acc);
        emitH(acc, lane, __builtin_amdgcn_readfirstlane(j0), S2, Q2, h2s);
      }
      const int jA = __builtin_amdgcn_readfirstlane(w*32);
      #pragma unroll
      for (int jj = 0; jj < 16; ++jj){ accA[jj] = b4[jA + jj]; accB[jj] = b4[jA + 16 + jj]; }
      #pragma unroll
      for (int half = 0; half < 2; ++half){
        __syncthreads();
        #pragma unroll
        for (int c = 0; c < 2; ++c){
          const int j0 = half*128 + w*32 + c*16;
          float acc[16];
          chunk16<128,256>(h2s, lane, W3, b3, j0, acc);
          const int j0u = __builtin_amdgcn_readfirstlane(j0);
          const int r0 = j0u - half*128;
          #pragma unroll
          for (int jj = 0; jj < 16; ++jj){
            float z = fmaxf(acc[jj]*g_st[S3+j0u+jj] + g_st[Q3+j0u+jj], 0.f);
            h3h[(r0+jj)*PTS + lane] = f2bf(z);
          }
        }
        __syncthreads();
        chunk16_acc<128,128>(h3h, lane, W4, w*32,      half*128, accA);
        chunk16_acc<128,128>(h3h, lane, W4, w*32 + 16, half*128, accB);
      }
    } else {
      const int j0u = __builtin_amdgcn_readfirstlane(w*64);
      const u16* q = z3ws + (size_t)b*16384 + (size_t)j0u*64 + lane;
      #pragma unroll 8
      for (int mm = 0; mm < 64; ++mm){
        const int m = j0u + mm;
        float z = bf2f(q[mm*64]);
        z = fmaxf(z*g_st[S3 + m] + g_st[Q3 + m], 0.f);
        h3s[m*PTS + lane] = f2bf(z);
      }
      __syncthreads();
      chunk16<256,128>(h3s, lane, W4, b4, w*32,      accA);
      chunk16<256,128>(h3s, lane, W4, b4, w*32 + 16, accB);
    }
    if (w == 0){
      long seg = -1;
      if (valid){
        if (inv64) seg = (long)((const long long*)unq_inv_v)[p];
        else       seg = (long)((const int*)unq_inv_v)[p];
      }
      seg_s[lane] = (seg >= 0 && seg < U &&
                     loEl + seg*128 + 128 <= hiEl) ? (int)seg : -1;
    }
    __syncthreads();
    {
      float4* dst = (float4*)&z4[lane*Z4S + w*32];
      dst[0] = make_float4(accA[ 0],accA[ 1],accA[ 2],accA[ 3]);
      dst[1] = make_float4(accA[ 4],accA[ 5],accA[ 6],accA[ 7]);
      dst[2] = make_float4(accA[ 8],accA[ 9],accA[10],accA[11]);
      dst[3] = make_float4(accA[12],accA[13],accA[14],accA[15]);
      dst[4] = make_float4(accB[ 0],accB[ 1],accB[ 2],accB[ 3]);
      dst[5] = make_float4(accB[ 4],accB[ 5],accB[ 6],accB[ 7]);
      dst[6] = make_float4(accB[ 8],accB[ 9],accB[10],accB[11]);
      dst[7] = make_float4(accB[12],accB[13],accB[14],accB[15]);
    }
    __syncthreads();
    #pragma unroll 4
    for (int pt2 = 0; pt2 < 64; pt2 += 2){
      const int pt = pt2 + (tid >> 7);
      const int f = tid & 127;
      const int sg = seg_s[pt];
      if (sg >= 0)
        atomicMaxF32(out + loEl + (long)sg*128 + f, z4[pt*Z4S + f]);
    }
    __syncthreads();
  }
}

extern "C" void kernel_launch(void* const* d_in, const int* in_sizes, int n_in,
                              void* d_out, int out_size, void* d_ws, size_t ws_size,
                              hipStream_t stream)
{
  const float* x       = (const float*)d_in[0];
  const void*  unq     = d_in[2];
  const void*  unq_inv = d_in[3];
  const float* bn_g[4] = {(const float*)d_in[4], (const float*)d_in[6], (const float*)d_in[8], (const float*)d_in[10]};
  const float* bn_b[4] = {(const float*)d_in[5], (const float*)d_in[7], (const float*)d_in[9], (const float*)d_in[11]};
  const float* W1 = (const float*)d_in[12]; const float* b1 = (const float*)d_in[13];
  const float* W2 = (const float*)d_in[14]; const float* b2 = (const float*)d_in[15];
  const float* W3 = (const float*)d_in[16]; const float* b3 = (const float*)d_in[17];
  const float* W4 = (const float*)d_in[18]; const float* b4 = (const float*)d_in[19];

  const int N = in_sizes[0] / 3;
  float* out = (float*)d_out;
  const float invN = 1.0f / (float)N;
  const long outSize = (long)out_size;

  const size_t nb64 = (size_t)((N + 63) / 64);
  u16* z3ws = (u16*)d_ws;
  u16* z2ws = z3ws + nb64*16384;
  const size_t need1 = nb64*16384*sizeof(u16);
  const size_t need2 = nb64*(16384+8192)*sizeof(u16);
  const int wsLevel = (ws_size >= need2) ? 2 : (ws_size >= need1) ? 1 : 0;

  kreset<<<1, 1024, 0, stream>>>();
  ksniff_inv<<<1, 1024, 0, stream>>>((const u32*)unq_inv, (long)N);
  ksegU<<<512, 256, 0, stream>>>(unq_inv, N);
  ksniff_unq<<<1, 1024, 0, stream>>>((const u32*)unq);
  kpoolinit<<<2048, 256, 0, stream>>>(out, outSize);

  kstats0<<<1024, 256, 0, stream>>>(x, N);
  kfin<<<1, 256, 0, stream>>>(3, S0, Q0, bn_g[0], bn_b[0], invN);
  kfin1<<<1, 64, 0, stream>>>(bn_g[1], bn_b[1], W1, b1, invN);

  if (wsLevel == 2){
    kprep<<<36, 256, 0, stream>>>(W2, W3, W4);
    kpass2m<<<2048, 256, 0, stream>>>(x, W1, b1, b2, z2ws, N);
    kfin<<<1, 256, 0, stream>>>(128, S2, Q2, bn_g[2], bn_b[2], invN);
    kpass3m<<<1536, 256, 0, stream>>>(z2ws, b3, z3ws, N);
    kfin<<<1, 256, 0, stream>>>(256, S3, Q3, bn_g[3], bn_b[3], invN);
    kpass4m<<<1024, 256, 0, stream>>>(unq_inv, b4, z3ws, out, N, outSize);
  } else if (wsLevel == 1){
    kpass2<0><<<2048, 256, 0, stream>>>(x, W1,b1,W2,b2, z2ws, N);
    kfin<<<1, 256, 0, stream>>>(128, S2, Q2, bn_g[2], bn_b[2], invN);
    kpass3<1><<<1536, 256, 0, stream>>>(x, W1,b1,W2,b2,W3,b3, z3ws, N);
    kfin<<<1, 256, 0, stream>>>(256, S3, Q3, bn_g[3], bn_b[3], invN);
    kpass4<2><<<1024, 256, 0, stream>>>(x, unq_inv, W1,b1,W2,b2,W3,b3,W4,b4, z3ws, out, N, outSize);
  } else {
    kpass2<0><<<2048, 256, 0, stream>>>(x, W1,b1,W2,b2, z2ws, N);
    kfin<<<1, 256, 0, stream>>>(128, S2, Q2, bn_g[2], bn_b[2], invN);
    kpass3<0><<<1536, 256, 0, stream>>>(x, W1,b1,W2,b2,W3,b3, z3ws, N);
    kfin<<<1, 256, 0, stream>>>(256, S3, Q3, bn_g[3], bn_b[3], invN);
    kpass4<0><<<1024, 256, 0, stream>>>(x, unq_inv, W1,b1,W2,b2,W3,b3,W4,b4, z3ws, out, N, outSize);
  }

  kunq<<<2048, 256, 0, stream>>>(out, unq, outSize);
}